// Round 2
// baseline (1202.233 us; speedup 1.0000x reference)
//
#include <hip/hip_runtime.h>

#define IN_F    2048
#define OUT_F   2048
#define BK      64      // k-block (mask window)
#define BM      256     // rows of x per workgroup
#define BN      64      // output cols per workgroup (one o-block)
#define NKB     32      // IN_F / BK
#define NOB     32      // OUT_F / BN
#define THREADS 256

// Block-sparse masked linear: y = x @ (mask*W)^T + b.
// mask has 64x64 block structure (block-constant); detect nonzero blocks by
// sampling the block corner, then compute only those K-blocks.
// Per-thread tile 8x8 (thread grid 32m x 8n). LDS tiles XOR-swizzled so all
// ds_read_b128 are <=2-way bank aliased (free).
__global__ __launch_bounds__(THREADS, 2)
void rl_sparse_fp32(const float* __restrict__ x,
                    const float* __restrict__ w,
                    const float* __restrict__ mask,
                    const float* __restrict__ bias,
                    float* __restrict__ out)
{
    __shared__ __align__(16) float xs[BM * BK];   // x tile, row m, chunk (k>>2)^((m>>3)&3)
    __shared__ __align__(16) float wsb[BN * BK];  // w_eff tile, row n, chunk (k>>2)^((n>>3)&3)

    const int tid = threadIdx.x;
    const int ob  = blockIdx.x & (NOB - 1);   // o-block fastest -> x m-tile L2 reuse
    const int mt  = blockIdx.x >> 5;
    const size_t m_base = (size_t)mt * BM;
    const int n_base = ob * BN;

    // --- nonzero k-block bitmask (identical in every wave; no divergence) ---
    const int lane = tid & 63;
    float mv = 0.0f;
    if (lane < NKB)
        mv = mask[(size_t)n_base * IN_F + (size_t)lane * BK];
    unsigned long long kbits = __ballot(mv != 0.0f);

    // compute-phase thread mapping
    const int tn = tid & 7;        // n group: n0 = tn*8
    const int tm = tid >> 3;       // m group: m0 = tm*8 (0..31)
    const int selx = tm & 3;       // xs swizzle selector for this thread's rows
    const int selw = tn & 3;       // wsb swizzle selector

    // staging-phase thread mapping (16 float4 chunks per 64-col row)
    const int sc = tid & 15;
    const int sr = tid >> 4;

    float acc[8][8];
    #pragma unroll
    for (int i = 0; i < 8; ++i)
        #pragma unroll
        for (int j = 0; j < 8; ++j) acc[i][j] = 0.0f;

    while (kbits) {
        const int kb = __ffsll(kbits) - 1;
        kbits &= (kbits - 1);
        const size_t kcol = (size_t)kb * BK;

        // ---- global -> regs (issued before the sync so latency overlaps the
        //      tail of other waves' compute) ----
        const float* xg = x + m_base * IN_F + kcol + sc * 4;
        float4 vx[BM / 16];
        #pragma unroll
        for (int it = 0; it < BM / 16; ++it)
            vx[it] = *(const float4*)(xg + (size_t)(sr + 16 * it) * IN_F);

        const float* wg = w    + (size_t)(n_base + sr) * IN_F + kcol + sc * 4;
        const float* mg = mask + (size_t)(n_base + sr) * IN_F + kcol + sc * 4;
        float4 vw[BN / 16];
        #pragma unroll
        for (int it = 0; it < BN / 16; ++it) {
            float4 a = *(const float4*)(wg + (size_t)(16 * it) * IN_F);
            float4 b = *(const float4*)(mg + (size_t)(16 * it) * IN_F);
            a.x *= b.x; a.y *= b.y; a.z *= b.z; a.w *= b.w;  // elementwise mask
            vw[it] = a;
        }

        __syncthreads();   // previous tile's compute done before overwrite

        // ---- regs -> LDS (XOR-swizzled chunks; 2-way write aliasing = free) ----
        #pragma unroll
        for (int it = 0; it < BM / 16; ++it) {
            const int r = sr + 16 * it;
            const int ch = sc ^ ((r >> 3) & 3);
            *(float4*)(&xs[r * BK + ch * 4]) = vx[it];
        }
        #pragma unroll
        for (int it = 0; it < BN / 16; ++it) {
            const int r = sr + 16 * it;
            const int ch = sc ^ ((r >> 3) & 3);
            *(float4*)(&wsb[r * BK + ch * 4]) = vw[it];
        }
        __syncthreads();

        // ---- compute: 16 k-chunks of 4; per chunk 16 ds_read_b128 + 256 FMA ----
        const float* xrow = &xs[tm * 8 * BK];
        const float* wrow = &wsb[tn * 8 * BK];
        #pragma unroll 4
        for (int kc = 0; kc < 16; ++kc) {
            const int offx = ((kc ^ selx) << 2);
            const int offw = ((kc ^ selw) << 2);
            float4 xv[8], wv[8];
            #pragma unroll
            for (int i = 0; i < 8; ++i)
                xv[i] = *(const float4*)(xrow + i * BK + offx);
            #pragma unroll
            for (int j = 0; j < 8; ++j)
                wv[j] = *(const float4*)(wrow + j * BK + offw);
            #pragma unroll
            for (int i = 0; i < 8; ++i)
                #pragma unroll
                for (int j = 0; j < 8; ++j) {
                    acc[i][j] += xv[i].x * wv[j].x;
                    acc[i][j] += xv[i].y * wv[j].y;
                    acc[i][j] += xv[i].z * wv[j].z;
                    acc[i][j] += xv[i].w * wv[j].w;
                }
        }
    }

    // ---- epilogue: + bias, coalesced float4 stores ----
    const float4 b0 = *(const float4*)(bias + n_base + tn * 8);
    const float4 b1 = *(const float4*)(bias + n_base + tn * 8 + 4);
    #pragma unroll
    for (int i = 0; i < 8; ++i) {
        const size_t row = m_base + tm * 8 + i;
        float* op = out + row * OUT_F + n_base + tn * 8;
        float4 o0 = make_float4(acc[i][0] + b0.x, acc[i][1] + b0.y,
                                acc[i][2] + b0.z, acc[i][3] + b0.w);
        float4 o1 = make_float4(acc[i][4] + b1.x, acc[i][5] + b1.y,
                                acc[i][6] + b1.z, acc[i][7] + b1.w);
        *(float4*)(op)     = o0;
        *(float4*)(op + 4) = o1;
    }
}

extern "C" void kernel_launch(void* const* d_in, const int* in_sizes, int n_in,
                              void* d_out, int out_size, void* d_ws, size_t ws_size,
                              hipStream_t stream) {
    const float* x    = (const float*)d_in[0];
    const float* w    = (const float*)d_in[1];
    const float* mask = (const float*)d_in[2];
    const float* bias = (const float*)d_in[3];
    float* out = (float*)d_out;

    const int M = in_sizes[0] / IN_F;          // 32768
    dim3 grid((M / BM) * NOB);                 // 128 m-tiles * 32 o-blocks = 4096
    rl_sparse_fp32<<<grid, THREADS, 0, stream>>>(x, w, mask, bias, out);
}